// Round 1
// baseline (705.719 us; speedup 1.0000x reference)
//
#include <hip/hip_runtime.h>
#include <math.h>

#define NROWS 32768   // B*S
#define DD    1024
#define EE    640     // G*V
#define VV    320
#define BM    32
#define BK    16

// Each block: 32 rows x all 640 cols. 256 threads = 4 waves; wave rt owns rows
// rt*8..rt*8+7; lane ct owns cols ct+64j, j=0..9 (j<5 -> group 0, j>=5 -> group 1).
__global__ __launch_bounds__(256, 2) void fused_vq(
    const float* __restrict__ x, const float* __restrict__ W,
    const float* __restrict__ b, const float* __restrict__ cb,
    const float* __restrict__ gum, float* __restrict__ out,
    float* __restrict__ probs_acc)
{
    __shared__ float xs[BK][BM];      // x tile, transposed: xs[kk][r]
    __shared__ float wt[BK][EE];      // W tile
    __shared__ float probs_blk[EE];   // per-block prob sums

    const int t  = threadIdx.x;
    const int ct = t & 63;
    const int rt = t >> 6;            // wave id
    const int n0 = blockIdx.x * BM;

    for (int c = t; c < EE; c += 256) probs_blk[c] = 0.f;

    float acc[8][10];
    #pragma unroll
    for (int i = 0; i < 8; ++i)
        #pragma unroll
        for (int j = 0; j < 10; ++j) acc[i][j] = 0.f;

    // hoisted W-tile staging offsets (10 float4 per thread per K-tile)
    int wkk[10], wc4[10];
    #pragma unroll
    for (int s = 0; s < 10; ++s) {
        int e4 = t + 256 * s;         // 0..2559 float4 slots (16*160)
        wkk[s] = e4 / 160;
        wc4[s] = e4 % 160;
    }

    for (int k0 = 0; k0 < DD; k0 += BK) {
        __syncthreads();
        if (t < 128) {
            int r = t >> 2, c4 = t & 3;
            float4 v = *reinterpret_cast<const float4*>(
                &x[(size_t)(n0 + r) * DD + k0 + c4 * 4]);
            xs[c4 * 4 + 0][r] = v.x;
            xs[c4 * 4 + 1][r] = v.y;
            xs[c4 * 4 + 2][r] = v.z;
            xs[c4 * 4 + 3][r] = v.w;
        }
        #pragma unroll
        for (int s = 0; s < 10; ++s) {
            *reinterpret_cast<float4*>(&wt[wkk[s]][wc4[s] * 4]) =
                *reinterpret_cast<const float4*>(
                    &W[(size_t)(k0 + wkk[s]) * EE + wc4[s] * 4]);
        }
        __syncthreads();
        #pragma unroll
        for (int kk = 0; kk < BK; ++kk) {
            float4 a0 = *reinterpret_cast<const float4*>(&xs[kk][rt * 8]);
            float4 a1 = *reinterpret_cast<const float4*>(&xs[kk][rt * 8 + 4]);
            float xv[8] = {a0.x, a0.y, a0.z, a0.w, a1.x, a1.y, a1.z, a1.w};
            float wv[10];
            #pragma unroll
            for (int j = 0; j < 10; ++j) wv[j] = wt[kk][ct + 64 * j];
            #pragma unroll
            for (int i = 0; i < 8; ++i)
                #pragma unroll
                for (int j = 0; j < 10; ++j)
                    acc[i][j] = fmaf(xv[i], wv[j], acc[i][j]);
        }
    }

    // bias (zeros in this problem, but keep it faithful)
    {
        float bv[10];
        #pragma unroll
        for (int j = 0; j < 10; ++j) bv[j] = b[ct + 64 * j];
        #pragma unroll
        for (int i = 0; i < 8; ++i)
            #pragma unroll
            for (int j = 0; j < 10; ++j) acc[i][j] += bv[j];
    }

    // ---- epilogue: per (row, g) argmax(logit+gumbel) + clean softmax ----
    int   idxr[8][2];
    float pacc[10];
    #pragma unroll
    for (int j = 0; j < 10; ++j) pacc[j] = 0.f;

    #pragma unroll
    for (int i = 0; i < 8; ++i) {
        const size_t n = (size_t)(n0 + rt * 8 + i);
        #pragma unroll
        for (int g = 0; g < 2; ++g) {
            float m1 = -1e30f; int bi = 0x7fffffff;
            float m2 = -1e30f;
            float zr[5];
            #pragma unroll
            for (int jj = 0; jj < 5; ++jj) {
                float z = acc[i][g * 5 + jj];
                zr[jj] = z;
                float gv = gum[(n * 2 + g) * VV + ct + 64 * jj];
                float zg = z + gv;
                int col = ct + 64 * jj;
                if (zg > m1) { m1 = zg; bi = col; }   // ascending col: > keeps first
                m2 = fmaxf(m2, z);
            }
            // wave-wide argmax (first index wins ties, numpy semantics)
            #pragma unroll
            for (int off = 1; off < 64; off <<= 1) {
                float om = __shfl_xor(m1, off);
                int   ob = __shfl_xor(bi, off);
                if (om > m1 || (om == m1 && ob < bi)) { m1 = om; bi = ob; }
            }
            #pragma unroll
            for (int off = 1; off < 64; off <<= 1)
                m2 = fmaxf(m2, __shfl_xor(m2, off));
            float s = 0.f, ex[5];
            #pragma unroll
            for (int jj = 0; jj < 5; ++jj) {
                ex[jj] = __expf(zr[jj] - m2);
                s += ex[jj];
            }
            #pragma unroll
            for (int off = 1; off < 64; off <<= 1) s += __shfl_xor(s, off);
            float inv = 1.f / s;
            #pragma unroll
            for (int jj = 0; jj < 5; ++jj) pacc[g * 5 + jj] += ex[jj] * inv;
            idxr[i][g] = bi;   // wave-uniform
        }
    }

    #pragma unroll
    for (int j = 0; j < 10; ++j)
        atomicAdd(&probs_blk[ct + 64 * j], pacc[j]);

    // ---- quantized output: copy selected codebook rows (wave-local idx) ----
    #pragma unroll
    for (int i = 0; i < 8; ++i) {
        const size_t n = (size_t)(n0 + rt * 8 + i);
        float4* orow = reinterpret_cast<float4*>(out) + n * 256;
        #pragma unroll
        for (int m = 0; m < 4; ++m) {
            int f = ct + 64 * m;          // 0..255, g uniform per m
            int g = f >> 7;
            int idx = idxr[i][g];
            const float4* crow =
                reinterpret_cast<const float4*>(cb) + ((size_t)g * VV + idx) * 128;
            orow[f] = crow[f & 127];
        }
    }

    __syncthreads();
    for (int c = t; c < EE; c += 256)
        atomicAdd(&probs_acc[c], probs_blk[c]);
}

__global__ void perp_kernel(const float* __restrict__ probs_acc,
                            float* __restrict__ outp)
{
    __shared__ float s0[4], s1[4];
    int t = threadIdx.x;   // 256
    float p0 = 0.f, p1 = 0.f;
    for (int c = t; c < EE; c += 256) {
        float a = probs_acc[c] * (1.0f / NROWS);
        float v = a * logf(a + 1e-7f);
        if (c < VV) p0 += v; else p1 += v;
    }
    #pragma unroll
    for (int off = 1; off < 64; off <<= 1) {
        p0 += __shfl_xor(p0, off);
        p1 += __shfl_xor(p1, off);
    }
    if ((t & 63) == 0) { s0[t >> 6] = p0; s1[t >> 6] = p1; }
    __syncthreads();
    if (t == 0) {
        float a0 = s0[0] + s0[1] + s0[2] + s0[3];
        float a1 = s1[0] + s1[1] + s1[2] + s1[3];
        outp[0] = 0.5f * (expf(-a0) + expf(-a1));
    }
}

extern "C" void kernel_launch(void* const* d_in, const int* in_sizes, int n_in,
                              void* d_out, int out_size, void* d_ws, size_t ws_size,
                              hipStream_t stream)
{
    const float* x   = (const float*)d_in[0];
    const float* W   = (const float*)d_in[1];
    const float* b   = (const float*)d_in[2];
    const float* cb  = (const float*)d_in[3];
    const float* gum = (const float*)d_in[4];
    float* out = (float*)d_out;
    float* probs_acc = (float*)d_ws;

    hipMemsetAsync(probs_acc, 0, EE * sizeof(float), stream);
    fused_vq<<<NROWS / BM, 256, 0, stream>>>(x, W, b, cb, gum, out, probs_acc);
    perp_kernel<<<1, 256, 0, stream>>>(probs_acc, out + (out_size - 1));
}

// Round 2
// 255.821 us; speedup vs baseline: 2.7586x; 2.7586x over previous
//
#include <hip/hip_runtime.h>
#include <math.h>

#define NROWS 32768
#define DD    1024
#define EE    640
#define VV    320
#define BM    128
#define BK    32
#define KT    32      // DD/BK
#define CTN   40      // EE/16
#define SPLIT_ELEMS (DD*EE)           // bf16 elems per split
#define SPLIT_BYTES (SPLIT_ELEMS*2)

typedef __attribute__((ext_vector_type(8))) short short8;
typedef __attribute__((ext_vector_type(4))) short short4v;
typedef __attribute__((ext_vector_type(4))) float float4v;

static __device__ __forceinline__ unsigned short f2bf(float f) {
    unsigned int u = __float_as_uint(f);
    return (unsigned short)((u + 0x7fffu + ((u >> 16) & 1u)) >> 16); // RNE
}
static __device__ __forceinline__ float bf2f(unsigned short h) {
    return __uint_as_float(((unsigned int)h) << 16);
}

// Pack W [K=1024][N=640] fp32 -> 2 bf16 splits in MFMA fragment layout:
// frag(kt, ct): lane l, elem e  <=  W[kt*32 + (l>>4)*8 + e][ct*16 + (l&15)]
__global__ void pack_w(const float* __restrict__ W, unsigned short* __restrict__ bp)
{
    const int t = threadIdx.x;
    const int tile = blockIdx.x * 4 + (t >> 6);   // 0..1279 = kt*40+ct
    const int lane = t & 63;
    const int kt = tile / CTN, ct = tile % CTN;
    const int k0 = kt * BK + (lane >> 4) * 8;
    const int col = ct * 16 + (lane & 15);
    unsigned short v1[8], v2[8];
    #pragma unroll
    for (int e = 0; e < 8; ++e) {
        float w = W[(size_t)(k0 + e) * EE + col];
        unsigned short b1 = f2bf(w);
        float r = w - bf2f(b1);
        v1[e] = b1;
        v2[e] = f2bf(r);
    }
    const size_t off = ((size_t)tile * 64 + lane) * 8;
    *(short8*)(bp + off)               = *(const short8*)v1;
    *(short8*)(bp + SPLIT_ELEMS + off) = *(const short8*)v2;
}

// 256 blocks x 512 threads. Block: 128 rows x all 640 cols.
// Wave w: row-group rg=w>>2 (64 rows), col-group cg=w&3 (160 cols = 10 frags).
__global__ __launch_bounds__(512, 2) void fused_mfma(
    const float* __restrict__ x, const unsigned short* __restrict__ bp,
    const float* __restrict__ bias, const float* __restrict__ cb,
    const float* __restrict__ gum, float* __restrict__ out,
    float* __restrict__ probs_acc)
{
    __shared__ unsigned short As[2][3][BM*BK];   // A splits, fragment layout
    __shared__ float probs_blk[EE];
    __shared__ float pmax[4][BM];
    __shared__ float psum[4][BM];
    __shared__ int   pidx[4][BM];
    __shared__ int   fidx[BM][2];
    __shared__ float finv[BM][2];

    const int t    = threadIdx.x;
    const int lane = t & 63;
    const int w    = t >> 6;
    const int rg   = w >> 2;
    const int cg   = w & 3;
    const int n0   = blockIdx.x * BM;

    float4v acc[4][10];
    #pragma unroll
    for (int rf = 0; rf < 4; ++rf)
        #pragma unroll
        for (int ct = 0; ct < 10; ++ct)
            acc[rf][ct] = (float4v)0.f;

    // staging geometry: slot0 = t (rows 0..63), slot1 = t+512 (rows 64..127)
    const int row0 = t >> 3, kq0 = t & 7;
    const int base0 = (row0 >> 4)*512 + ((row0 & 15) + ((kq0 >> 1) << 4))*8 + ((kq0 & 1) << 2);
    const int base1 = base0 + 4*512;             // row+64 -> rowfrag+4
    const float* xr0 = x + (size_t)(n0 + row0) * DD + kq0 * 4;
    const float* xr1 = xr0 + (size_t)64 * DD;

    auto writeSplits = [&](int bb, int base, float4 v) {
        float vv[4] = {v.x, v.y, v.z, v.w};
        short4v s1, s2, s3;
        #pragma unroll
        for (int e = 0; e < 4; ++e) {
            unsigned short b1 = f2bf(vv[e]);
            float r1 = vv[e] - bf2f(b1);
            unsigned short b2 = f2bf(r1);
            float r2 = r1 - bf2f(b2);
            s1[e] = (short)b1; s2[e] = (short)b2; s3[e] = (short)f2bf(r2);
        }
        *(short4v*)&As[bb][0][base] = s1;
        *(short4v*)&As[bb][1][base] = s2;
        *(short4v*)&As[bb][2][base] = s3;
    };

    // prologue
    writeSplits(0, base0, *(const float4*)(xr0));
    writeSplits(0, base1, *(const float4*)(xr1));
    __syncthreads();

    const unsigned short* bp2 = bp + SPLIT_ELEMS;

    for (int kt = 0; kt < KT; ++kt) {
        const int bb = kt & 1;
        const bool more = (kt + 1 < KT);
        float4 p0, p1;
        if (more) {                               // issue-early
            p0 = *(const float4*)(xr0 + (kt + 1) * BK);
            p1 = *(const float4*)(xr1 + (kt + 1) * BK);
        }
        short8 af[4][3];
        #pragma unroll
        for (int rf = 0; rf < 4; ++rf)
            #pragma unroll
            for (int s = 0; s < 3; ++s)
                af[rf][s] = *(const short8*)&As[bb][s][(rg*4 + rf)*512 + lane*8];

        const size_t fb = (((size_t)kt*CTN + cg*10)*64 + lane)*8;
        #pragma unroll
        for (int ct = 0; ct < 10; ++ct) {
            short8 b1 = *(const short8*)(bp  + fb + ct*512);
            short8 b2 = *(const short8*)(bp2 + fb + ct*512);
            #pragma unroll
            for (int rf = 0; rf < 4; ++rf) {
                float4v a = acc[rf][ct];
                a = __builtin_amdgcn_mfma_f32_16x16x32_bf16(af[rf][0], b1, a, 0, 0, 0);
                a = __builtin_amdgcn_mfma_f32_16x16x32_bf16(af[rf][1], b1, a, 0, 0, 0);
                a = __builtin_amdgcn_mfma_f32_16x16x32_bf16(af[rf][2], b1, a, 0, 0, 0);
                a = __builtin_amdgcn_mfma_f32_16x16x32_bf16(af[rf][0], b2, a, 0, 0, 0);
                a = __builtin_amdgcn_mfma_f32_16x16x32_bf16(af[rf][1], b2, a, 0, 0, 0);
                acc[rf][ct] = a;
            }
        }
        if (more) {                               // write-late
            writeSplits(bb ^ 1, base0, p0);
            writeSplits(bb ^ 1, base1, p1);
        }
        __syncthreads();
    }

    // bias (zeros in this problem; kept faithful)
    {
        float bv[10];
        #pragma unroll
        for (int ct = 0; ct < 10; ++ct) bv[ct] = bias[cg*160 + ct*16 + (lane & 15)];
        #pragma unroll
        for (int rf = 0; rf < 4; ++rf)
            #pragma unroll
            for (int ct = 0; ct < 10; ++ct) {
                acc[rf][ct][0] += bv[ct]; acc[rf][ct][1] += bv[ct];
                acc[rf][ct][2] += bv[ct]; acc[rf][ct][3] += bv[ct];
            }
    }

    // ---- Phase A: gumbel-argmax partial + clean exp-sum partial ----
    const int g = cg >> 1;                        // group 0: cols 0..319
    const int goff0 = (cg & 1)*160 + (lane & 15); // col within group
    #pragma unroll
    for (int rf = 0; rf < 4; ++rf) {
        #pragma unroll
        for (int r = 0; r < 4; ++r) {
            const int rowA = rg*64 + rf*16 + ((lane >> 4) << 2) + r;
            const float* grow = gum + ((size_t)(n0 + rowA)*2 + g)*VV + goff0;
            float m1 = -1e30f; int bi = 0; float es = 0.f;
            #pragma unroll
            for (int ct = 0; ct < 10; ++ct) {
                float z  = acc[rf][ct][r];
                float zg = z + grow[ct*16];
                if (zg > m1) { m1 = zg; bi = goff0 + ct*16; }
                es += __expf(z);
            }
            #pragma unroll
            for (int off = 1; off < 16; off <<= 1) {
                float om = __shfl_xor(m1, off);
                int   ob = __shfl_xor(bi, off);
                if (om > m1 || (om == m1 && ob < bi)) { m1 = om; bi = ob; }
                es += __shfl_xor(es, off);
            }
            if ((lane & 15) == 0) {
                pmax[cg][rowA] = m1; pidx[cg][rowA] = bi; psum[cg][rowA] = es;
            }
        }
    }
    __syncthreads();

    // ---- Phase B: cross-wave combine ----
    if (t < 256) {
        const int row = t & 127, gg = t >> 7;
        const float mA = pmax[gg*2][row], mB = pmax[gg*2+1][row];
        const int   iA = pidx[gg*2][row], iB = pidx[gg*2+1][row];
        fidx[row][gg] = (mB > mA || (mB == mA && iB < iA)) ? iB : iA;
        finv[row][gg] = 1.f / (psum[gg*2][row] + psum[gg*2+1][row]);
    }
    for (int c = t; c < EE; c += 512) probs_blk[c] = 0.f;
    __syncthreads();

    // ---- Phase C: probs accumulation ----
    float pacc[10];
    #pragma unroll
    for (int ct = 0; ct < 10; ++ct) pacc[ct] = 0.f;
    #pragma unroll
    for (int rf = 0; rf < 4; ++rf) {
        #pragma unroll
        for (int r = 0; r < 4; ++r) {
            const int rowA = rg*64 + rf*16 + ((lane >> 4) << 2) + r;
            const float inv = finv[rowA][g];
            #pragma unroll
            for (int ct = 0; ct < 10; ++ct)
                pacc[ct] += __expf(acc[rf][ct][r]) * inv;
        }
    }
    #pragma unroll
    for (int off = 16; off < 64; off <<= 1)
        #pragma unroll
        for (int ct = 0; ct < 10; ++ct)
            pacc[ct] += __shfl_xor(pacc[ct], off);
    if (lane < 16) {
        #pragma unroll
        for (int ct = 0; ct < 10; ++ct)
            atomicAdd(&probs_blk[cg*160 + ct*16 + lane], pacc[ct]);
    }
    __syncthreads();

    for (int c = t; c < EE; c += 512)
        atomicAdd(&probs_acc[c], probs_blk[c]);

    // ---- output: codebook gather ----
    for (int i = t; i < BM*256; i += 512) {
        const int row = i >> 8, f4 = i & 255;
        const int gg  = f4 >> 7;
        const int idx = fidx[row][gg];
        const float4 v = *(const float4*)&cb[((size_t)gg*VV + idx)*512 + (size_t)(f4 & 127)*4];
        *(float4*)&out[(size_t)(n0 + row)*DD + (size_t)f4*4] = v;
    }
}

__global__ void perp_kernel(const float* __restrict__ probs_acc,
                            float* __restrict__ outp)
{
    __shared__ float s0[4], s1[4];
    int t = threadIdx.x;   // 256
    float p0 = 0.f, p1 = 0.f;
    for (int c = t; c < EE; c += 256) {
        float a = probs_acc[c] * (1.0f / NROWS);
        float v = a * logf(a + 1e-7f);
        if (c < VV) p0 += v; else p1 += v;
    }
    #pragma unroll
    for (int off = 1; off < 64; off <<= 1) {
        p0 += __shfl_xor(p0, off);
        p1 += __shfl_xor(p1, off);
    }
    if ((t & 63) == 0) { s0[t >> 6] = p0; s1[t >> 6] = p1; }
    __syncthreads();
    if (t == 0) {
        float a0 = s0[0] + s0[1] + s0[2] + s0[3];
        float a1 = s1[0] + s1[1] + s1[2] + s1[3];
        outp[0] = 0.5f * (expf(-a0) + expf(-a1));
    }
}

extern "C" void kernel_launch(void* const* d_in, const int* in_sizes, int n_in,
                              void* d_out, int out_size, void* d_ws, size_t ws_size,
                              hipStream_t stream)
{
    const float* x   = (const float*)d_in[0];
    const float* W   = (const float*)d_in[1];
    const float* b   = (const float*)d_in[2];
    const float* cb  = (const float*)d_in[3];
    const float* gum = (const float*)d_in[4];
    float* out = (float*)d_out;

    unsigned short* bp = (unsigned short*)d_ws;
    float* probs_acc = (float*)((char*)d_ws + 2*(size_t)SPLIT_BYTES);

    hipMemsetAsync(probs_acc, 0, EE * sizeof(float), stream);
    pack_w<<<320, 256, 0, stream>>>(W, bp);
    fused_mfma<<<NROWS / BM, 512, 0, stream>>>(x, bp, b, cb, gum, out, probs_acc);
    perp_kernel<<<1, 256, 0, stream>>>(probs_acc, out + (out_size - 1));
}

// Round 3
// 135.739 us; speedup vs baseline: 5.1991x; 1.8847x over previous
//
#include <hip/hip_runtime.h>
#include <math.h>

#define NROWS 32768
#define DD    1024
#define EE    640
#define VV    320
#define BM    128
#define BK    32
#define KT    32      // DD/BK
#define CTN   40      // EE/16

typedef __attribute__((ext_vector_type(8))) short short8;
typedef __attribute__((ext_vector_type(4))) short short4v;
typedef __attribute__((ext_vector_type(4))) float float4v;

static __device__ __forceinline__ unsigned short f2bf(float f) {
    unsigned int u = __float_as_uint(f);
    return (unsigned short)((u + 0x7fffu + ((u >> 16) & 1u)) >> 16); // RNE
}

static __device__ __forceinline__ void gload_lds16(const void* g, void* l) {
    __builtin_amdgcn_global_load_lds(
        (const __attribute__((address_space(1))) unsigned int*)g,
        (__attribute__((address_space(3))) unsigned int*)l, 16, 0, 0);
}

// Pack W [K=1024][N=640] fp32 -> single bf16 split, MFMA fragment layout:
// frag(kt, ct): lane l, elem e  <=  W[kt*32 + (l>>4)*8 + e][ct*16 + (l&15)]
__global__ void pack_w(const float* __restrict__ W, unsigned short* __restrict__ bp)
{
    const int t = threadIdx.x;
    const int tile = blockIdx.x * 4 + (t >> 6);   // 0..1279 = kt*40+ct
    const int lane = t & 63;
    const int kt = tile / CTN, ct = tile % CTN;
    const int k0 = kt * BK + (lane >> 4) * 8;
    const int col = ct * 16 + (lane & 15);
    unsigned short v1[8];
    #pragma unroll
    for (int e = 0; e < 8; ++e)
        v1[e] = f2bf(W[(size_t)(k0 + e) * EE + col]);
    *(short8*)(bp + ((size_t)tile * 64 + lane) * 8) = *(const short8*)v1;
}

// 256 blocks x 512 threads. Block: 128 rows x all 640 cols.
// Wave w: rg=w>>2 (64 rows), cg=w&3 (160 cols = 10 frags). acc[4][10].
__global__ __launch_bounds__(512, 2) void fused_mfma(
    const float* __restrict__ x, const unsigned short* __restrict__ bp,
    const float* __restrict__ bias, const float* __restrict__ cb,
    const float* __restrict__ gum, float* __restrict__ out,
    float* __restrict__ probs_acc)
{
    __shared__ unsigned short Bs[2][BK * EE];     // 2 x 40KB, fragment layout
    __shared__ unsigned short As[2][BM * BK];     // 2 x 8KB, fragment layout
    __shared__ float probs_blk[EE];
    __shared__ float pmax[4][BM];
    __shared__ float psum[4][BM];
    __shared__ int   pidx[4][BM];
    __shared__ int   fidx[BM][2];
    __shared__ float finv[BM][2];

    const int t    = threadIdx.x;
    const int lane = t & 63;
    const int w    = t >> 6;
    const int rg   = w >> 2;
    const int cg   = w & 3;
    const int n0   = blockIdx.x * BM;

    float4v acc[4][10];
    #pragma unroll
    for (int rf = 0; rf < 4; ++rf)
        #pragma unroll
        for (int ct = 0; ct < 10; ++ct)
            acc[rf][ct] = (float4v)0.f;

    // A staging: thread t handles float4 quads t (rows 0..63) and t+512 (rows 64..127)
    const int row0 = t >> 3, kq0 = t & 7;
    const int abase0 = (row0 >> 4)*512 + ((row0 & 15) + ((kq0 >> 1) << 4))*8 + ((kq0 & 1) << 2);
    const int abase1 = abase0 + 4*512;            // row+64 -> rowfrag+4
    const float* xr0 = x + (size_t)(n0 + row0) * DD + kq0 * 4;
    const float* xr1 = xr0 + (size_t)64 * DD;

    auto writeA = [&](int bb, int base, float4 v) {
        short4v s1;
        s1[0] = (short)f2bf(v.x); s1[1] = (short)f2bf(v.y);
        s1[2] = (short)f2bf(v.z); s1[3] = (short)f2bf(v.w);
        *(short4v*)&As[bb][base] = s1;
    };
    // B staging: 2560 16B-slots per kt; thread t stages slots s*512+t
    auto stageB = [&](int bb, int kt) {
        const unsigned short* src = bp + (size_t)kt * (BK * EE);
        #pragma unroll
        for (int s = 0; s < 5; ++s) {
            const int q = s * 512 + t;
            gload_lds16(src + (size_t)q * 8, &Bs[bb][q * 8]);
        }
    };

    // prologue: stage kt=0
    stageB(0, 0);
    writeA(0, abase0, *(const float4*)(xr0));
    writeA(0, abase1, *(const float4*)(xr1));
    __syncthreads();

    for (int kt = 0; kt < KT; ++kt) {
        const int bb = kt & 1;
        const bool more = (kt + 1 < KT);
        float4 p0, p1;
        if (more) {
            stageB(bb ^ 1, kt + 1);               // async into other buffer
            p0 = *(const float4*)(xr0 + (kt + 1) * BK);
            p1 = *(const float4*)(xr1 + (kt + 1) * BK);
        }
        short8 af[4];
        #pragma unroll
        for (int rf = 0; rf < 4; ++rf)
            af[rf] = *(const short8*)&As[bb][(rg*4 + rf)*512 + lane*8];
        #pragma unroll
        for (int ct = 0; ct < 10; ++ct) {
            short8 bf = *(const short8*)&Bs[bb][((cg*10 + ct)*64 + lane)*8];
            #pragma unroll
            for (int rf = 0; rf < 4; ++rf)
                acc[rf][ct] = __builtin_amdgcn_mfma_f32_16x16x32_bf16(af[rf], bf, acc[rf][ct], 0, 0, 0);
        }
        if (more) {
            writeA(bb ^ 1, abase0, p0);
            writeA(bb ^ 1, abase1, p1);
        }
        __syncthreads();                          // drains vmcnt (B staging) too
    }

    // bias (zeros in this problem; kept faithful)
    {
        float bv[10];
        #pragma unroll
        for (int ct = 0; ct < 10; ++ct) bv[ct] = bias[cg*160 + ct*16 + (lane & 15)];
        #pragma unroll
        for (int rf = 0; rf < 4; ++rf)
            #pragma unroll
            for (int ct = 0; ct < 10; ++ct) {
                acc[rf][ct][0] += bv[ct]; acc[rf][ct][1] += bv[ct];
                acc[rf][ct][2] += bv[ct]; acc[rf][ct][3] += bv[ct];
            }
    }

    // ---- Phase A: gumbel-argmax partial + clean exp-sum partial ----
    const int g = cg >> 1;
    const int goff0 = (cg & 1)*160 + (lane & 15);
    #pragma unroll
    for (int rf = 0; rf < 4; ++rf) {
        #pragma unroll
        for (int r = 0; r < 4; ++r) {
            const int rowA = rg*64 + rf*16 + ((lane >> 4) << 2) + r;
            const float* grow = gum + ((size_t)(n0 + rowA)*2 + g)*VV + goff0;
            float m1 = -1e30f; int bi = 0; float es = 0.f;
            #pragma unroll
            for (int ct = 0; ct < 10; ++ct) {
                float z  = acc[rf][ct][r];
                float zg = z + grow[ct*16];
                if (zg > m1) { m1 = zg; bi = goff0 + ct*16; }
                es += __expf(z);
            }
            #pragma unroll
            for (int off = 1; off < 16; off <<= 1) {
                float om = __shfl_xor(m1, off);
                int   ob = __shfl_xor(bi, off);
                if (om > m1 || (om == m1 && ob < bi)) { m1 = om; bi = ob; }
                es += __shfl_xor(es, off);
            }
            if ((lane & 15) == 0) {
                pmax[cg][rowA] = m1; pidx[cg][rowA] = bi; psum[cg][rowA] = es;
            }
        }
    }
    __syncthreads();

    // ---- Phase B: cross-wave combine ----
    if (t < 256) {
        const int row = t & 127, gg = t >> 7;
        const float mA = pmax[gg*2][row], mB = pmax[gg*2+1][row];
        const int   iA = pidx[gg*2][row], iB = pidx[gg*2+1][row];
        fidx[row][gg] = (mB > mA || (mB == mA && iB < iA)) ? iB : iA;
        finv[row][gg] = 1.f / (psum[gg*2][row] + psum[gg*2+1][row]);
    }
    for (int c = t; c < EE; c += 512) probs_blk[c] = 0.f;
    __syncthreads();

    // ---- Phase C: probs accumulation ----
    float pacc[10];
    #pragma unroll
    for (int ct = 0; ct < 10; ++ct) pacc[ct] = 0.f;
    #pragma unroll
    for (int rf = 0; rf < 4; ++rf) {
        #pragma unroll
        for (int r = 0; r < 4; ++r) {
            const int rowA = rg*64 + rf*16 + ((lane >> 4) << 2) + r;
            const float inv = finv[rowA][g];
            #pragma unroll
            for (int ct = 0; ct < 10; ++ct)
                pacc[ct] += __expf(acc[rf][ct][r]) * inv;
        }
    }
    #pragma unroll
    for (int off = 16; off < 64; off <<= 1)
        #pragma unroll
        for (int ct = 0; ct < 10; ++ct)
            pacc[ct] += __shfl_xor(pacc[ct], off);
    if (lane < 16) {
        #pragma unroll
        for (int ct = 0; ct < 10; ++ct)
            atomicAdd(&probs_blk[cg*160 + ct*16 + lane], pacc[ct]);
    }
    __syncthreads();

    for (int c = t; c < EE; c += 512)
        atomicAdd(&probs_acc[c], probs_blk[c]);

    // ---- output: codebook gather ----
    for (int i = t; i < BM*256; i += 512) {
        const int row = i >> 8, f4 = i & 255;
        const int gg  = f4 >> 7;
        const int idx = fidx[row][gg];
        const float4 v = *(const float4*)&cb[((size_t)gg*VV + idx)*512 + (size_t)(f4 & 127)*4];
        *(float4*)&out[(size_t)(n0 + row)*DD + (size_t)f4*4] = v;
    }
}

__global__ void perp_kernel(const float* __restrict__ probs_acc,
                            float* __restrict__ outp)
{
    __shared__ float s0[4], s1[4];
    int t = threadIdx.x;   // 256
    float p0 = 0.f, p1 = 0.f;
    for (int c = t; c < EE; c += 256) {
        float a = probs_acc[c] * (1.0f / NROWS);
        float v = a * logf(a + 1e-7f);
        if (c < VV) p0 += v; else p1 += v;
    }
    #pragma unroll
    for (int off = 1; off < 64; off <<= 1) {
        p0 += __shfl_xor(p0, off);
        p1 += __shfl_xor(p1, off);
    }
    if ((t & 63) == 0) { s0[t >> 6] = p0; s1[t >> 6] = p1; }
    __syncthreads();
    if (t == 0) {
        float a0 = s0[0] + s0[1] + s0[2] + s0[3];
        float a1 = s1[0] + s1[1] + s1[2] + s1[3];
        outp[0] = 0.5f * (expf(-a0) + expf(-a1));
    }
}

extern "C" void kernel_launch(void* const* d_in, const int* in_sizes, int n_in,
                              void* d_out, int out_size, void* d_ws, size_t ws_size,
                              hipStream_t stream)
{
    const float* x   = (const float*)d_in[0];
    const float* W   = (const float*)d_in[1];
    const float* b   = (const float*)d_in[2];
    const float* cb  = (const float*)d_in[3];
    const float* gum = (const float*)d_in[4];
    float* out = (float*)d_out;

    unsigned short* bp = (unsigned short*)d_ws;                  // 1.31 MB packed W
    float* probs_acc = (float*)((char*)d_ws + (size_t)DD*EE*2);

    hipMemsetAsync(probs_acc, 0, EE * sizeof(float), stream);
    pack_w<<<320, 256, 0, stream>>>(W, bp);
    fused_mfma<<<NROWS / BM, 512, 0, stream>>>(x, bp, b, cb, gum, out, probs_acc);
    perp_kernel<<<1, 256, 0, stream>>>(probs_acc, out + (out_size - 1));
}